// Round 1
// baseline (179.863 us; speedup 1.0000x reference)
//
#include <hip/hip_runtime.h>
#include <hip/hip_bf16.h>
#include <stdint.h>

typedef __bf16 bf16x8 __attribute__((ext_vector_type(8)));
typedef float  f32x4  __attribute__((ext_vector_type(4)));

__device__ __forceinline__ unsigned short f2bf(float f) {
    union { float f; unsigned u; } v; v.f = f;
    unsigned r = v.u + 0x7fffu + ((v.u >> 16) & 1u);   // RNE
    return (unsigned short)(r >> 16);
}

// async global->LDS, 16B per lane, wave-uniform LDS base (+lane*16 in HW)
__device__ __forceinline__ void async16(void* lds, const void* g) {
    __builtin_amdgcn_global_load_lds(
        (const __attribute__((address_space(1))) unsigned int*)g,
        (__attribute__((address_space(3))) unsigned int*)lds, 16, 0, 0);
}

// ---------------- weight fp32 -> bf16 (layouts unchanged: [3][512][256]) ----
__global__ __launch_bounds__(256) void convert_w_kernel(
    const float* __restrict__ wq, const float* __restrict__ wk,
    const float* __restrict__ wv, unsigned short* __restrict__ wb)
{
    const int n = 3 * 512 * 256;
    int t = blockIdx.z;
    const float* src = (t == 0) ? wq : (t == 1) ? wk : wv;
    int i = blockIdx.x * 256 + threadIdx.x;
    if (i < n) wb[(size_t)t * n + i] = f2bf(src[i]);
}

// ---------------- x [bc][256][HW] f32 -> xT [bc*HW][256] bf16 ---------------
__global__ __launch_bounds__(256) void transpose_kernel(
    const float* __restrict__ x, unsigned short* __restrict__ xT, int HW)
{
    __shared__ unsigned short tile[64][65];
    int hw0 = blockIdx.x * 64;
    int c0  = blockIdx.y * 64;
    int b   = blockIdx.z;
    int tx = threadIdx.x & 63;
    int ty = threadIdx.x >> 6;                     // 0..3
    const float* xp = x + (size_t)b * 256 * HW;
#pragma unroll
    for (int i = 0; i < 16; ++i) {
        int c = c0 + ty * 16 + i;
        tile[ty * 16 + i][tx] = f2bf(xp[(size_t)c * HW + hw0 + tx]);
    }
    __syncthreads();
    unsigned short* op = xT + ((size_t)b * HW + hw0) * 256 + c0;
#pragma unroll
    for (int i = 0; i < 16; ++i) {
        int r = ty * 16 + i;                       // local hw row
        op[(size_t)r * 256 + tx] = tile[tx][r];
    }
}

// ---------------- QKV GEMM: out[b][o][hw] = W[o][:]·xT[n][:] + bias[o] ------
// M=512, K=256, N=bc*HW. 128x128 tile, BK=32, 4 waves, 64x64/wave, bf16 MFMA.
__global__ __launch_bounds__(256) void qkv_gemm_kernel(
    const unsigned short* __restrict__ wbq, const unsigned short* __restrict__ wbk,
    const unsigned short* __restrict__ wbv,
    const float* __restrict__ bq, const float* __restrict__ bk, const float* __restrict__ bv,
    const unsigned short* __restrict__ xT,
    float* __restrict__ qo, float* __restrict__ ko, float* __restrict__ vo,
    int lgHW)
{
    int z = blockIdx.z;
    const unsigned short* Wm = (z == 0) ? wbq : (z == 1) ? wbk : wbv;
    const float* bias        = (z == 0) ? bq  : (z == 1) ? bk  : bv;
    float* out               = (z == 0) ? qo  : (z == 1) ? ko  : vo;

    __shared__ unsigned short smem[8192];   // A: 4096 ushorts (8KB), B: 4096
    unsigned short* As = smem;
    unsigned short* Bs = smem + 4096;

    int tid  = threadIdx.x;
    int lane = tid & 63;
    int wid  = tid >> 6;                    // 0..3
    int wr   = wid >> 1, wc = wid & 1;
    int l15  = lane & 15;
    int kg   = lane >> 4;                   // 0..3

    int bm0 = blockIdx.y * 128;             // o
    int bn0 = blockIdx.x * 128;             // n

    f32x4 acc[4][4];
#pragma unroll
    for (int i = 0; i < 4; ++i)
#pragma unroll
        for (int j = 0; j < 4; ++j) acc[i][j] = (f32x4){0.f, 0.f, 0.f, 0.f};

    // staging rows for this lane (fragment order: slot = (mt*64+lane)*16B)
    int aRow0 = bm0 + (2 * wid)     * 16 + l15;
    int aRow1 = bm0 + (2 * wid + 1) * 16 + l15;
    int bRow0 = bn0 + (2 * wid)     * 16 + l15;
    int bRow1 = bn0 + (2 * wid + 1) * 16 + l15;

    for (int k0 = 0; k0 < 256; k0 += 32) {
        int kk = k0 + kg * 8;
        async16(As + (2 * wid)     * 512, Wm + (size_t)aRow0 * 256 + kk);
        async16(As + (2 * wid + 1) * 512, Wm + (size_t)aRow1 * 256 + kk);
        async16(Bs + (2 * wid)     * 512, xT + (size_t)bRow0 * 256 + kk);
        async16(Bs + (2 * wid + 1) * 512, xT + (size_t)bRow1 * 256 + kk);
        asm volatile("s_waitcnt vmcnt(0)" ::: "memory");
        __syncthreads();

        bf16x8 af[4], bg[4];
#pragma unroll
        for (int mi = 0; mi < 4; ++mi)
            af[mi] = *reinterpret_cast<const bf16x8*>(As + ((wr * 4 + mi) * 64 + lane) * 8);
#pragma unroll
        for (int ni = 0; ni < 4; ++ni)
            bg[ni] = *reinterpret_cast<const bf16x8*>(Bs + ((wc * 4 + ni) * 64 + lane) * 8);
#pragma unroll
        for (int mi = 0; mi < 4; ++mi)
#pragma unroll
            for (int ni = 0; ni < 4; ++ni)
                acc[mi][ni] = __builtin_amdgcn_mfma_f32_16x16x32_bf16(
                    af[mi], bg[ni], acc[mi][ni], 0, 0, 0);
        __syncthreads();
    }

    int HWm1 = (1 << lgHW) - 1;
#pragma unroll
    for (int mi = 0; mi < 4; ++mi) {
        int obase = bm0 + wr * 64 + mi * 16 + kg * 4;
#pragma unroll
        for (int ni = 0; ni < 4; ++ni) {
            int n  = bn0 + wc * 64 + ni * 16 + l15;
            int b  = n >> lgHW;
            int hw = n & HWm1;
#pragma unroll
            for (int r = 0; r < 4; ++r) {
                int o = obase + r;
                out[(((size_t)b * 512 + o) << lgHW) + hw] = acc[mi][ni][r] + bias[o];
            }
        }
    }
}

// ---------------- 3x3 local attention + relu + spatial-mean accumulation ----
__global__ __launch_bounds__(256) void attn_kernel(
    const float* __restrict__ qb, const float* __restrict__ kb, const float* __restrict__ vb,
    const float* __restrict__ bk, const float* __restrict__ bv,
    const float* __restrict__ relh, const float* __restrict__ relw,
    float* __restrict__ feat, int H, int W, int lgW, int b0, float invHW)
{
    int c  = blockIdx.y;
    int bl = blockIdx.z;
    int HW = H * W;
    int hw = blockIdx.x * 256 + threadIdx.x;
    int h = hw >> lgW, w = hw & (W - 1);
    size_t base = ((size_t)bl * 512 + c) * HW;
    float q   = qb[base + hw];
    float bkc = bk[c], bvc = bv[c];
    float r3[3];
    {
        const float* rs = (c < 256) ? (relh + c * 3) : (relw + (c - 256) * 3);
        r3[0] = rs[0]; r3[1] = rs[1]; r3[2] = rs[2];
    }
    bool ish = (c < 256);
    float s[9], vv[9];
    int t = 0;
#pragma unroll
    for (int dy = -1; dy <= 1; ++dy) {
        int y = h + dy;
        bool yin = (unsigned)y < (unsigned)H;
#pragma unroll
        for (int dx = -1; dx <= 1; ++dx) {
            int x = w + dx;
            bool in = yin && ((unsigned)x < (unsigned)W);
            float kkv, vt;
            if (in) { int off = (y << lgW) + x; kkv = kb[base + off]; vt = vb[base + off]; }
            else    { kkv = bkc; vt = bvc; }
            float rr = ish ? r3[dy + 1] : r3[dx + 1];
            s[t] = q * (kkv + rr);
            vv[t] = vt;
            ++t;
        }
    }
    float m = s[0];
#pragma unroll
    for (int i = 1; i < 9; ++i) m = fmaxf(m, s[i]);
    float num = 0.f, den = 0.f;
#pragma unroll
    for (int i = 0; i < 9; ++i) { float p = __expf(s[i] - m); num += p * vv[i]; den += p; }
    float y = fmaxf(num / den, 0.f) * invHW;

#pragma unroll
    for (int off = 32; off; off >>= 1) y += __shfl_down(y, off, 64);
    __shared__ float red[4];
    int lane = threadIdx.x & 63, wvi = threadIdx.x >> 6;
    if (lane == 0) red[wvi] = y;
    __syncthreads();
    if (threadIdx.x == 0) {
        float sum = red[0] + red[1] + red[2] + red[3];
        atomicAdd(&feat[(size_t)(b0 + bl) * 512 + c], sum);
    }
}

// ---------------- classifiers: one wave per output row ----------------------
__global__ __launch_bounds__(256) void logits_kernel(
    const float* __restrict__ feat,
    const float* __restrict__ ws, const float* __restrict__ bs,
    const float* __restrict__ wf, const float* __restrict__ bff,
    const float* __restrict__ wo, const float* __restrict__ bo,
    float* __restrict__ out)
{
    __shared__ float f[2048];
    for (int i = threadIdx.x; i < 2048; i += 256) f[i] = feat[i];
    __syncthreads();
    int lane = threadIdx.x & 63;
    int wid  = threadIdx.x >> 6;
    long long row = (long long)blockIdx.x * 4 + wid;
    const float* wm; float bias; size_t obase; int ostride;
    if (row < 64500) {
        wm = ws + (size_t)row * 512; bias = bs[row]; obase = (size_t)row; ostride = 64500;
    } else if (row < 64500 + 489) {
        long long r = row - 64500;
        wm = wf + (size_t)r * 512; bias = bff[r]; obase = 258000 + (size_t)r; ostride = 489;
    } else if (row < 64500 + 489 + 140) {
        long long r = row - 64989;
        wm = wo + (size_t)r * 512; bias = bo[r]; obase = 259956 + (size_t)r; ostride = 140;
    } else return;

    f32x4 w1 = *(const f32x4*)(wm + lane * 4);
    f32x4 w2 = *(const f32x4*)(wm + 256 + lane * 4);
    float accs[4];
#pragma unroll
    for (int b = 0; b < 4; ++b) {
        const float* fb = f + b * 512 + lane * 4;
        f32x4 f1 = *(const f32x4*)fb;
        f32x4 f2 = *(const f32x4*)(fb + 256);
        accs[b] = w1.x * f1.x + w1.y * f1.y + w1.z * f1.z + w1.w * f1.w
                + w2.x * f2.x + w2.y * f2.y + w2.z * f2.z + w2.w * f2.w;
    }
#pragma unroll
    for (int off = 32; off; off >>= 1)
#pragma unroll
        for (int b = 0; b < 4; ++b) accs[b] += __shfl_down(accs[b], off, 64);
    if (lane == 0)
#pragma unroll
        for (int b = 0; b < 4; ++b) out[obase + (size_t)b * ostride] = accs[b] + bias;
}

extern "C" void kernel_launch(void* const* d_in, const int* in_sizes, int n_in,
                              void* d_out, int out_size, void* d_ws, size_t ws_size,
                              hipStream_t stream)
{
    const float* xs[3] = { (const float*)d_in[0], (const float*)d_in[1], (const float*)d_in[2] };
    const float* wq  = (const float*)d_in[3];
    const float* bq  = (const float*)d_in[4];
    const float* wk  = (const float*)d_in[5];
    const float* bk  = (const float*)d_in[6];
    const float* wv  = (const float*)d_in[7];
    const float* bv  = (const float*)d_in[8];
    const float* relh = (const float*)d_in[9];
    const float* relw = (const float*)d_in[10];
    const float* ws  = (const float*)d_in[11];
    const float* bs  = (const float*)d_in[12];
    const float* wf  = (const float*)d_in[13];
    const float* bff = (const float*)d_in[14];
    const float* wo  = (const float*)d_in[15];
    const float* bo  = (const float*)d_in[16];
    float* out = (float*)d_out;

    char* wsb = (char*)d_ws;
    float* feat = (float*)wsb;                                   // 8 KB
    unsigned short* wb = (unsigned short*)(wsb + 8192);          // 3*3*512*256 bf16

    size_t fixed = 8192 + (size_t)3 * 3 * 512 * 256 * 2;
    // per-batch: xT 2 MB + q/k/v 3*8 MB (p3-sized, reused for p4/p5)
    int bc = 4;
    while (bc > 1 && fixed + (size_t)bc * (2097152 + 3 * 8388608) > ws_size) bc >>= 1;

    size_t off = fixed;
    unsigned short* xT = (unsigned short*)(wsb + off); off += (size_t)bc * 2097152;
    float* qb  = (float*)(wsb + off); off += (size_t)bc * 8388608;
    float* kb2 = (float*)(wsb + off); off += (size_t)bc * 8388608;
    float* vb2 = (float*)(wsb + off);

    hipMemsetAsync(feat, 0, 4 * 512 * sizeof(float), stream);
    convert_w_kernel<<<dim3(1536, 1, 3), 256, 0, stream>>>(wq, wk, wv, wb);

    const int Hs[3]   = {64, 32, 16};
    const int lgWs[3] = {6, 5, 4};
    for (int lvl = 0; lvl < 3; ++lvl) {
        int H = Hs[lvl], Wd = H, HW = H * Wd;
        int lgW = lgWs[lvl], lgHW = 2 * lgW;
        const unsigned short* wbq_l = wb + ((size_t)0 * 3 + lvl) * 131072;
        const unsigned short* wbk_l = wb + ((size_t)1 * 3 + lvl) * 131072;
        const unsigned short* wbv_l = wb + ((size_t)2 * 3 + lvl) * 131072;
        const float* bq_l = bq + lvl * 512;
        const float* bk_l = bk + lvl * 512;
        const float* bv_l = bv + lvl * 512;
        const float* relh_l = relh + lvl * 256 * 3;
        const float* relw_l = relw + lvl * 256 * 3;
        for (int b0 = 0; b0 < 4; b0 += bc) {
            transpose_kernel<<<dim3(HW / 64, 4, bc), 256, 0, stream>>>(
                xs[lvl] + (size_t)b0 * 256 * HW, xT, HW);
            int N = bc * HW;
            qkv_gemm_kernel<<<dim3(N / 128, 4, 3), 256, 0, stream>>>(
                wbq_l, wbk_l, wbv_l, bq_l, bk_l, bv_l, xT, qb, kb2, vb2, lgHW);
            attn_kernel<<<dim3(HW / 256, 512, bc), 256, 0, stream>>>(
                qb, kb2, vb2, bk_l, bv_l, relh_l, relw_l, feat, H, Wd, lgW, b0, 1.0f / HW);
        }
    }
    const int rows = 64500 + 489 + 140;
    logits_kernel<<<dim3((rows + 3) / 4), 256, 0, stream>>>(feat, ws, bs, wf, bff, wo, bo, out);
}